// Round 3
// baseline (1604.879 us; speedup 1.0000x reference)
//
#include <hip/hip_runtime.h>

typedef long long ll;
typedef __attribute__((ext_vector_type(8))) short short8;
typedef __attribute__((ext_vector_type(4))) float f32x4;
constexpr int HID = 256;
constexpr int LDSS = 264;   // LDS row stride in shorts: 528B, 16B-aligned, breaks pow2 banks

__device__ inline ushort f2bf(float f){
  uint u = __float_as_uint(f);
  u += 0x7FFFu + ((u >> 16) & 1u);
  return (ushort)(u >> 16);
}

// ---------------- diagnostics ----------------
__global__ void k_diag(float* out, int n, float val){
  int i = blockIdx.x*256 + threadIdx.x;
  if (i < n) out[i] = val;
}

// flag=1 if edge_index is int64 (all high words of first 2048 entries zero)
__global__ void k_detect(const int* ei, int* flag){
  __shared__ int bad;
  if (threadIdx.x == 0) bad = 0;
  __syncthreads();
  for (int i = threadIdx.x; i < 2048; i += 256)
    if (ei[2*i+1] != 0) bad = 1;
  __syncthreads();
  if (threadIdx.x == 0) *flag = bad ? 0 : 1;
}

// ---------------- graph preprocessing ----------------
__global__ void k_count(const int* ei, ll E, const int* flag, int* cnt){
  ll i = (ll)blockIdx.x*256 + threadIdx.x;
  if (i >= E) return;
  int f = *flag;
  int d = f ? (int)((const ll*)ei)[E + i] : ei[E + i];
  atomicAdd(&cnt[d], 1);
}

__global__ void k_scan1024(const int* cnt, int* row_ptr, int n){
  __shared__ int s[1024];
  int t = threadIdx.x;
  int chunk = (n + 1023) >> 10;
  int lo = t*chunk, hi = min(lo + chunk, n);
  int sum = 0;
  for (int i = lo; i < hi; ++i) sum += cnt[i];
  s[t] = sum; __syncthreads();
  for (int off = 1; off < 1024; off <<= 1){
    int add = (t >= off) ? s[t - off] : 0;
    __syncthreads();
    s[t] += add;
    __syncthreads();
  }
  int run = (t == 0) ? 0 : s[t-1];
  for (int i = lo; i < hi; ++i){ row_ptr[i] = run; run += cnt[i]; }
  if (t == 0) row_ptr[n] = s[1023];
}

__global__ void k_dinv(const int* cnt, const float* x, float* dinv, float* xd, int n){
  int i = blockIdx.x*256 + threadIdx.x;
  if (i >= n) return;
  float dv = 1.0f / sqrtf((float)(cnt[i] + 1));
  dinv[i] = dv;
  xd[i] = x[i] * dv;
}

__global__ void k_place(const int* ei, ll E, const int* flag, int* fill, int* col){
  ll i = (ll)blockIdx.x*256 + threadIdx.x;
  if (i >= E) return;
  int f = *flag;
  int s, d;
  if (f){ const ll* e64 = (const ll*)ei; s = (int)e64[i]; d = (int)e64[E + i]; }
  else  { s = ei[i]; d = ei[E + i]; }
  int p = atomicAdd(&fill[d], 1);
  col[p] = s;
}

// layer 1 is rank-1: g[d] = xd[d] + sum_{s->d} xd[s]
__global__ void k_layer1(const float* __restrict__ xd, const int* __restrict__ row_ptr,
                         const int* __restrict__ col, float* __restrict__ g, int n){
  int i = blockIdx.x*256 + threadIdx.x;
  if (i >= n) return;
  float s = xd[i];
  int e0 = row_ptr[i], e1 = row_ptr[i+1];
  for (int e = e0; e < e1; ++e) s += xd[col[e]];
  g[i] = s;
}

// ---------------- W split: fp32 -> (hi,lo) bf16, MFMA-fragment-major ----------------
__global__ void k_splitW(const float* __restrict__ W, short* __restrict__ Bt){
  int idx = blockIdx.x*256 + threadIdx.x;
  if (idx >= 16*8*64) return;
  int nb = idx >> 9, kc = (idx >> 6) & 7, l = idx & 63;
  short8 hi, lo;
  #pragma unroll
  for (int j = 0; j < 8; ++j){
    int k = kc*32 + ((l >> 4) * 8) + j;
    int c = nb*16 + (l & 15);
    float wv = W[k*HID + c];
    ushort h = f2bf(wv);
    float hf = __uint_as_float((uint)h << 16);
    hi[j] = (short)h;
    lo[j] = (short)f2bf(wv - hf);
  }
  ((short8*)Bt)[idx] = hi;
  ((short8*)Bt)[8192 + idx] = lo;
}

// ---------------- MFMA GEMM: ts = relu-transform(Ain) @ W * dinv_row ----------------
template<int MODE>
__global__ __launch_bounds__(256, 2) void k_gemm_mfma(
  const float* __restrict__ Ain, const short* __restrict__ Bt,
  const float* __restrict__ bias, const float* __restrict__ W1,
  const float* __restrict__ dinv, float* __restrict__ ts, int n)
{
  __shared__ short Ah[64*LDSS];
  __shared__ short Al[64*LDSS];
  int t = threadIdx.x;
  int r0 = blockIdx.x * 64;

  #pragma unroll
  for (int i = 0; i < 8; ++i){
    int id  = i*256 + t;
    int row = id >> 5;
    int c16 = id & 31;
    int v   = r0 + row;
    short8 hi8 = {0,0,0,0,0,0,0,0}, lo8 = {0,0,0,0,0,0,0,0};
    if (v < n){
      float dv = dinv[v];
      float vals[8];
      if (MODE == 0){
        float gv = dv * Ain[v];
        const float4* wp = (const float4*)(W1 + c16*8);
        const float4* bp = (const float4*)(bias + c16*8);
        float4 w0 = wp[0], w1 = wp[1], b0 = bp[0], b1 = bp[1];
        vals[0]=fmaf(gv,w0.x,b0.x); vals[1]=fmaf(gv,w0.y,b0.y);
        vals[2]=fmaf(gv,w0.z,b0.z); vals[3]=fmaf(gv,w0.w,b0.w);
        vals[4]=fmaf(gv,w1.x,b1.x); vals[5]=fmaf(gv,w1.y,b1.y);
        vals[6]=fmaf(gv,w1.z,b1.z); vals[7]=fmaf(gv,w1.w,b1.w);
      } else {
        const float4* ap = (const float4*)(Ain + (size_t)v*HID + c16*8);
        const float4* bp = (const float4*)(bias + c16*8);
        float4 a0 = ap[0], a1 = ap[1], b0 = bp[0], b1 = bp[1];
        vals[0]=fmaf(dv,a0.x,b0.x); vals[1]=fmaf(dv,a0.y,b0.y);
        vals[2]=fmaf(dv,a0.z,b0.z); vals[3]=fmaf(dv,a0.w,b0.w);
        vals[4]=fmaf(dv,a1.x,b1.x); vals[5]=fmaf(dv,a1.y,b1.y);
        vals[6]=fmaf(dv,a1.z,b1.z); vals[7]=fmaf(dv,a1.w,b1.w);
      }
      #pragma unroll
      for (int j = 0; j < 8; ++j){
        float a = fmaxf(vals[j], 0.f);
        ushort h = f2bf(a);
        float hf = __uint_as_float((uint)h << 16);
        hi8[j] = (short)h;
        lo8[j] = (short)f2bf(a - hf);
      }
    }
    int off = row*LDSS + c16*8;
    *(short8*)&Ah[off] = hi8;
    *(short8*)&Al[off] = lo8;
  }
  __syncthreads();

  int l = t & 63, w = t >> 6;
  const short8* Btv = (const short8*)Bt;
  f32x4 acc[4][4];
  #pragma unroll
  for (int m = 0; m < 4; ++m)
    #pragma unroll
    for (int nf = 0; nf < 4; ++nf)
      acc[m][nf] = (f32x4){0.f,0.f,0.f,0.f};

  for (int kc = 0; kc < 8; ++kc){
    short8 ah[4], al[4];
    #pragma unroll
    for (int m = 0; m < 4; ++m){
      int row = m*16 + (l & 15);
      int off = row*LDSS + (kc*4 + (l >> 4))*8;
      ah[m] = *(const short8*)&Ah[off];
      al[m] = *(const short8*)&Al[off];
    }
    #pragma unroll
    for (int nf = 0; nf < 4; ++nf){
      int nb = w*4 + nf;
      short8 bh = Btv[(size_t)(nb*8 + kc)*64 + l];
      short8 bl = Btv[(size_t)8192 + (nb*8 + kc)*64 + l];
      #pragma unroll
      for (int m = 0; m < 4; ++m){
        acc[m][nf] = __builtin_amdgcn_mfma_f32_16x16x32_bf16(ah[m], bh, acc[m][nf], 0,0,0);
        acc[m][nf] = __builtin_amdgcn_mfma_f32_16x16x32_bf16(al[m], bh, acc[m][nf], 0,0,0);
        acc[m][nf] = __builtin_amdgcn_mfma_f32_16x16x32_bf16(ah[m], bl, acc[m][nf], 0,0,0);
      }
    }
  }

  #pragma unroll
  for (int m = 0; m < 4; ++m){
    int rowb = r0 + m*16 + ((l >> 4)*4);
    #pragma unroll
    for (int r = 0; r < 4; ++r){
      int v = rowb + r;
      if (v < n){
        float dv = dinv[v];
        #pragma unroll
        for (int nf = 0; nf < 4; ++nf){
          int colb = w*64 + nf*16 + (l & 15);
          ts[(size_t)v*HID + colb] = dv * acc[m][nf][r];
        }
      }
    }
  }
}

// ---------------- propagate: acc[d] = ts[d] + sum_{e in CSR[d]} ts[col[e]] ----------------
// Deep-unrolled gather: 16 independent float4 loads in flight, 4 accumulators.
__global__ __launch_bounds__(256, 4) void k_scatter(
  const float* __restrict__ ts, const int* __restrict__ row_ptr,
  const int* __restrict__ col, float* __restrict__ acc, int n)
{
  int w = (int)((blockIdx.x*256 + threadIdx.x) >> 6);
  int lane = threadIdx.x & 63;
  if (w >= n) return;
  const float4* tsp = (const float4*)ts;
  int e0 = row_ptr[w], e1 = row_ptr[w+1];

  float4 a0 = tsp[(size_t)w*64 + lane];   // self-loop term
  float4 a1 = make_float4(0.f,0.f,0.f,0.f);
  float4 a2 = make_float4(0.f,0.f,0.f,0.f);
  float4 a3 = make_float4(0.f,0.f,0.f,0.f);

  int e = e0;
  for (; e + 16 <= e1; e += 16){
    int c[16];
    #pragma unroll
    for (int j = 0; j < 16; ++j) c[j] = col[e + j];
    float4 v[16];
    #pragma unroll
    for (int j = 0; j < 16; ++j) v[j] = tsp[(size_t)c[j]*64 + lane];
    #pragma unroll
    for (int j = 0; j < 16; j += 4){
      a0.x += v[j+0].x; a0.y += v[j+0].y; a0.z += v[j+0].z; a0.w += v[j+0].w;
      a1.x += v[j+1].x; a1.y += v[j+1].y; a1.z += v[j+1].z; a1.w += v[j+1].w;
      a2.x += v[j+2].x; a2.y += v[j+2].y; a2.z += v[j+2].z; a2.w += v[j+2].w;
      a3.x += v[j+3].x; a3.y += v[j+3].y; a3.z += v[j+3].z; a3.w += v[j+3].w;
    }
  }
  for (; e + 4 <= e1; e += 4){
    int c[4];
    #pragma unroll
    for (int j = 0; j < 4; ++j) c[j] = col[e + j];
    float4 v0 = tsp[(size_t)c[0]*64 + lane];
    float4 v1 = tsp[(size_t)c[1]*64 + lane];
    float4 v2 = tsp[(size_t)c[2]*64 + lane];
    float4 v3 = tsp[(size_t)c[3]*64 + lane];
    a0.x += v0.x; a0.y += v0.y; a0.z += v0.z; a0.w += v0.w;
    a1.x += v1.x; a1.y += v1.y; a1.z += v1.z; a1.w += v1.w;
    a2.x += v2.x; a2.y += v2.y; a2.z += v2.z; a2.w += v2.w;
    a3.x += v3.x; a3.y += v3.y; a3.z += v3.z; a3.w += v3.w;
  }
  for (; e < e1; ++e){
    int c = col[e];
    float4 v = tsp[(size_t)c*64 + lane];
    a0.x += v.x; a0.y += v.y; a0.z += v.z; a0.w += v.w;
  }

  a0.x += a1.x + a2.x + a3.x;
  a0.y += a1.y + a2.y + a3.y;
  a0.z += a1.z + a2.z + a3.z;
  a0.w += a1.w + a2.w + a3.w;
  ((float4*)acc)[(size_t)w*64 + lane] = a0;
}

// ---------------- final: out[v] = relu(dinv*acc + b) . Wc + bc ----------------
__global__ __launch_bounds__(256) void k_out(
  const float* __restrict__ acc, const float* __restrict__ bias,
  const float* __restrict__ Wc, const float* __restrict__ bc,
  const float* __restrict__ dinv, float* __restrict__ out, int n)
{
  int w = (int)((blockIdx.x*256 + threadIdx.x) >> 6);
  int lane = threadIdx.x & 63;
  if (w >= n) return;
  float dv = dinv[w];
  float4 a  = ((const float4*)acc)[(size_t)w*64 + lane];
  float4 bb = ((const float4*)bias)[lane];
  float4 wc = ((const float4*)Wc)[lane];
  float s = fmaxf(fmaf(dv, a.x, bb.x), 0.f)*wc.x
          + fmaxf(fmaf(dv, a.y, bb.y), 0.f)*wc.y
          + fmaxf(fmaf(dv, a.z, bb.z), 0.f)*wc.z
          + fmaxf(fmaf(dv, a.w, bb.w), 0.f)*wc.w;
  #pragma unroll
  for (int off = 32; off; off >>= 1) s += __shfl_down(s, off, 64);
  if (lane == 0) out[w] = s + bc[0];
}

// ---------------- launch ----------------
extern "C" void kernel_launch(void* const* d_in, const int* in_sizes, int n_in,
                              void* d_out, int out_size, void* d_ws, size_t ws_size,
                              hipStream_t stream)
{
  const float* x  = (const float*)d_in[0];
  const int*   ei = (const int*)d_in[1];
  const float* W1 = (const float*)d_in[2];
  const float* b1 = (const float*)d_in[3];
  const float* Wm = (const float*)d_in[4];
  const float* bm = (const float*)d_in[5];
  const float* Wc = (const float*)d_in[6];
  const float* bc = (const float*)d_in[7];
  float* out = (float*)d_out;
  const int N = in_sizes[0];
  const ll  E = in_sizes[1] / 2;

  char* ws = (char*)d_ws;
  size_t off = 0;
  auto carve = [&](size_t bytes)->char*{
    char* p = ws + off; off += (bytes + 255) & ~(size_t)255; return p;
  };
  int*   cnt     = (int*)  carve((size_t)N*4);
  int*   row_ptr = (int*)  carve((size_t)(N+1)*4);
  int*   fill    = (int*)  carve((size_t)N*4);
  float* dinv    = (float*)carve((size_t)N*4);
  float* xd      = (float*)carve((size_t)N*4);
  float* g       = (float*)carve((size_t)N*4);
  int*   flag    = (int*)  carve(256);
  short* Bt      = (short*)carve((size_t)2*8192*8*2);   // 256 KB
  int*   col     = (int*)  carve((size_t)E*4);
  float* ts      = (float*)carve((size_t)N*HID*4);
  float* acc     = (float*)carve((size_t)N*HID*4);
  if (off > ws_size){
    k_diag<<<(out_size+255)/256, 256, 0, stream>>>(out, out_size, (float)(ws_size >> 20));
    return;
  }

  hipMemsetAsync(cnt, 0, (size_t)N*4, stream);
  k_detect<<<1, 256, 0, stream>>>(ei, flag);
  int eblocks = (int)((E + 255) / 256);
  k_count<<<eblocks, 256, 0, stream>>>(ei, E, flag, cnt);
  k_scan1024<<<1, 1024, 0, stream>>>(cnt, row_ptr, N);
  k_dinv<<<(N+255)/256, 256, 0, stream>>>(cnt, x, dinv, xd, N);
  hipMemcpyAsync(fill, row_ptr, (size_t)N*4, hipMemcpyDeviceToDevice, stream);
  k_place<<<eblocks, 256, 0, stream>>>(ei, E, flag, fill, col);
  k_splitW<<<32, 256, 0, stream>>>(Wm, Bt);
  k_layer1<<<(N+255)/256, 256, 0, stream>>>(xd, row_ptr, col, g, N);

  int gblocks = (N + 63) / 64;
  int sblocks = (N + 3) / 4;
  k_gemm_mfma<0><<<gblocks, 256, 0, stream>>>(g, Bt, b1, W1, dinv, ts, N);
  k_scatter<<<sblocks, 256, 0, stream>>>(ts, row_ptr, col, acc, N);
  for (int l = 0; l < 8; ++l){
    k_gemm_mfma<1><<<gblocks, 256, 0, stream>>>(acc, Bt, bm, nullptr, dinv, ts, N);
    k_scatter<<<sblocks, 256, 0, stream>>>(ts, row_ptr, col, acc, N);
  }
  k_out<<<sblocks, 256, 0, stream>>>(acc, bm, Wc, bc, dinv, out, N);
}

// Round 4
// 1552.158 us; speedup vs baseline: 1.0340x; 1.0340x over previous
//
#include <hip/hip_runtime.h>

typedef long long ll;
typedef __attribute__((ext_vector_type(8))) short short8;
typedef __attribute__((ext_vector_type(4))) float f32x4;
constexpr int HID = 256;
constexpr int LDSS = 264;   // LDS row stride in shorts: 528B, 16B-aligned, breaks pow2 banks

__device__ inline ushort f2bf(float f){
  uint u = __float_as_uint(f);
  u += 0x7FFFu + ((u >> 16) & 1u);
  return (ushort)(u >> 16);
}

// ---------------- diagnostics ----------------
__global__ void k_diag(float* out, int n, float val){
  int i = blockIdx.x*256 + threadIdx.x;
  if (i < n) out[i] = val;
}

// flag=1 if edge_index is int64 (all high words of first 2048 entries zero)
__global__ void k_detect(const int* ei, int* flag){
  __shared__ int bad;
  if (threadIdx.x == 0) bad = 0;
  __syncthreads();
  for (int i = threadIdx.x; i < 2048; i += 256)
    if (ei[2*i+1] != 0) bad = 1;
  __syncthreads();
  if (threadIdx.x == 0) *flag = bad ? 0 : 1;
}

// ---------------- graph preprocessing ----------------
__global__ void k_count(const int* ei, ll E, const int* flag, int* cnt){
  ll i = (ll)blockIdx.x*256 + threadIdx.x;
  if (i >= E) return;
  int f = *flag;
  int d = f ? (int)((const ll*)ei)[E + i] : ei[E + i];
  atomicAdd(&cnt[d], 1);
}

__global__ void k_scan1024(const int* cnt, int* row_ptr, int n){
  __shared__ int s[1024];
  int t = threadIdx.x;
  int chunk = (n + 1023) >> 10;
  int lo = t*chunk, hi = min(lo + chunk, n);
  int sum = 0;
  for (int i = lo; i < hi; ++i) sum += cnt[i];
  s[t] = sum; __syncthreads();
  for (int off = 1; off < 1024; off <<= 1){
    int add = (t >= off) ? s[t - off] : 0;
    __syncthreads();
    s[t] += add;
    __syncthreads();
  }
  int run = (t == 0) ? 0 : s[t-1];
  for (int i = lo; i < hi; ++i){ row_ptr[i] = run; run += cnt[i]; }
  if (t == 0) row_ptr[n] = s[1023];
}

__global__ void k_dinv(const int* cnt, const float* x, float* dinv, float* xd, int n){
  int i = blockIdx.x*256 + threadIdx.x;
  if (i >= n) return;
  float dv = 1.0f / sqrtf((float)(cnt[i] + 1));
  dinv[i] = dv;
  xd[i] = x[i] * dv;
}

__global__ void k_place(const int* ei, ll E, const int* flag, int* fill, int* col){
  ll i = (ll)blockIdx.x*256 + threadIdx.x;
  if (i >= E) return;
  int f = *flag;
  int s, d;
  if (f){ const ll* e64 = (const ll*)ei; s = (int)e64[i]; d = (int)e64[E + i]; }
  else  { s = ei[i]; d = ei[E + i]; }
  int p = atomicAdd(&fill[d], 1);
  col[p] = s;
}

// layer 1 is rank-1: g[d] = xd[d] + sum_{s->d} xd[s]
__global__ void k_layer1(const float* __restrict__ xd, const int* __restrict__ row_ptr,
                         const int* __restrict__ col, float* __restrict__ g, int n){
  int i = blockIdx.x*256 + threadIdx.x;
  if (i >= n) return;
  float s = xd[i];
  int e0 = row_ptr[i], e1 = row_ptr[i+1];
  for (int e = e0; e < e1; ++e) s += xd[col[e]];
  g[i] = s;
}

// ---------------- W split: fp32 -> (hi,lo) bf16, MFMA-fragment-major ----------------
__global__ void k_splitW(const float* __restrict__ W, short* __restrict__ Bt){
  int idx = blockIdx.x*256 + threadIdx.x;
  if (idx >= 16*8*64) return;
  int nb = idx >> 9, kc = (idx >> 6) & 7, l = idx & 63;
  short8 hi, lo;
  #pragma unroll
  for (int j = 0; j < 8; ++j){
    int k = kc*32 + ((l >> 4) * 8) + j;
    int c = nb*16 + (l & 15);
    float wv = W[k*HID + c];
    ushort h = f2bf(wv);
    float hf = __uint_as_float((uint)h << 16);
    hi[j] = (short)h;
    lo[j] = (short)f2bf(wv - hf);
  }
  ((short8*)Bt)[idx] = hi;
  ((short8*)Bt)[8192 + idx] = lo;
}

// ---------------- MFMA GEMM: ts = relu-transform(Ain) @ W * dinv_row ----------------
template<int MODE>
__global__ __launch_bounds__(256, 2) void k_gemm_mfma(
  const float* __restrict__ Ain, const short* __restrict__ Bt,
  const float* __restrict__ bias, const float* __restrict__ W1,
  const float* __restrict__ dinv, float* __restrict__ ts, int n)
{
  __shared__ short Ah[64*LDSS];
  __shared__ short Al[64*LDSS];
  int t = threadIdx.x;
  int r0 = blockIdx.x * 64;

  #pragma unroll
  for (int i = 0; i < 8; ++i){
    int id  = i*256 + t;
    int row = id >> 5;
    int c16 = id & 31;
    int v   = r0 + row;
    short8 hi8 = {0,0,0,0,0,0,0,0}, lo8 = {0,0,0,0,0,0,0,0};
    if (v < n){
      float dv = dinv[v];
      float vals[8];
      if (MODE == 0){
        float gv = dv * Ain[v];
        const float4* wp = (const float4*)(W1 + c16*8);
        const float4* bp = (const float4*)(bias + c16*8);
        float4 w0 = wp[0], w1 = wp[1], b0 = bp[0], b1 = bp[1];
        vals[0]=fmaf(gv,w0.x,b0.x); vals[1]=fmaf(gv,w0.y,b0.y);
        vals[2]=fmaf(gv,w0.z,b0.z); vals[3]=fmaf(gv,w0.w,b0.w);
        vals[4]=fmaf(gv,w1.x,b1.x); vals[5]=fmaf(gv,w1.y,b1.y);
        vals[6]=fmaf(gv,w1.z,b1.z); vals[7]=fmaf(gv,w1.w,b1.w);
      } else {
        const float4* ap = (const float4*)(Ain + (size_t)v*HID + c16*8);
        const float4* bp = (const float4*)(bias + c16*8);
        float4 a0 = ap[0], a1 = ap[1], b0 = bp[0], b1 = bp[1];
        vals[0]=fmaf(dv,a0.x,b0.x); vals[1]=fmaf(dv,a0.y,b0.y);
        vals[2]=fmaf(dv,a0.z,b0.z); vals[3]=fmaf(dv,a0.w,b0.w);
        vals[4]=fmaf(dv,a1.x,b1.x); vals[5]=fmaf(dv,a1.y,b1.y);
        vals[6]=fmaf(dv,a1.z,b1.z); vals[7]=fmaf(dv,a1.w,b1.w);
      }
      #pragma unroll
      for (int j = 0; j < 8; ++j){
        float a = fmaxf(vals[j], 0.f);
        ushort h = f2bf(a);
        float hf = __uint_as_float((uint)h << 16);
        hi8[j] = (short)h;
        lo8[j] = (short)f2bf(a - hf);
      }
    }
    int off = row*LDSS + c16*8;
    *(short8*)&Ah[off] = hi8;
    *(short8*)&Al[off] = lo8;
  }
  __syncthreads();

  int l = t & 63, w = t >> 6;
  const short8* Btv = (const short8*)Bt;
  f32x4 acc[4][4];
  #pragma unroll
  for (int m = 0; m < 4; ++m)
    #pragma unroll
    for (int nf = 0; nf < 4; ++nf)
      acc[m][nf] = (f32x4){0.f,0.f,0.f,0.f};

  for (int kc = 0; kc < 8; ++kc){
    short8 ah[4], al[4];
    #pragma unroll
    for (int m = 0; m < 4; ++m){
      int row = m*16 + (l & 15);
      int off = row*LDSS + (kc*4 + (l >> 4))*8;
      ah[m] = *(const short8*)&Ah[off];
      al[m] = *(const short8*)&Al[off];
    }
    #pragma unroll
    for (int nf = 0; nf < 4; ++nf){
      int nb = w*4 + nf;
      short8 bh = Btv[(size_t)(nb*8 + kc)*64 + l];
      short8 bl = Btv[(size_t)8192 + (nb*8 + kc)*64 + l];
      #pragma unroll
      for (int m = 0; m < 4; ++m){
        acc[m][nf] = __builtin_amdgcn_mfma_f32_16x16x32_bf16(ah[m], bh, acc[m][nf], 0,0,0);
        acc[m][nf] = __builtin_amdgcn_mfma_f32_16x16x32_bf16(al[m], bh, acc[m][nf], 0,0,0);
        acc[m][nf] = __builtin_amdgcn_mfma_f32_16x16x32_bf16(ah[m], bl, acc[m][nf], 0,0,0);
      }
    }
  }

  #pragma unroll
  for (int m = 0; m < 4; ++m){
    int rowb = r0 + m*16 + ((l >> 4)*4);
    #pragma unroll
    for (int r = 0; r < 4; ++r){
      int v = rowb + r;
      if (v < n){
        float dv = dinv[v];
        #pragma unroll
        for (int nf = 0; nf < 4; ++nf){
          int colb = w*64 + nf*16 + (l & 15);
          ts[(size_t)v*HID + colb] = dv * acc[m][nf][r];
        }
      }
    }
  }
}

// ---------------- propagate (feature-half pass): acc_half[d] = ts_half[d] + sum ts_half[col[e]] ----
// Working set per pass = N*128*4 = 25.6 MB < 32 MB aggregate L2 -> better hit rate.
__global__ __launch_bounds__(256) void k_scatter_h(
  const float* __restrict__ ts, const int* __restrict__ row_ptr,
  const int* __restrict__ col, float* __restrict__ acc, int n, int half)
{
  int w = (int)((blockIdx.x*256 + threadIdx.x) >> 6);
  int lane = threadIdx.x & 63;
  if (w >= n) return;
  const float2* tsp = ((const float2*)ts) + (size_t)half*64 + lane;  // row c at + c*128
  int e0 = row_ptr[w], e1 = row_ptr[w+1];

  float2 a0 = tsp[(size_t)w*128];   // self-loop term
  float2 a1 = make_float2(0.f,0.f);
  float2 a2 = make_float2(0.f,0.f);
  float2 a3 = make_float2(0.f,0.f);

  int e = e0;
  for (; e + 8 <= e1; e += 8){
    int c0=col[e+0], c1=col[e+1], c2=col[e+2], c3=col[e+3];
    int c4=col[e+4], c5=col[e+5], c6=col[e+6], c7=col[e+7];
    float2 v0=tsp[(size_t)c0*128], v1=tsp[(size_t)c1*128];
    float2 v2=tsp[(size_t)c2*128], v3=tsp[(size_t)c3*128];
    float2 v4=tsp[(size_t)c4*128], v5=tsp[(size_t)c5*128];
    float2 v6=tsp[(size_t)c6*128], v7=tsp[(size_t)c7*128];
    a0.x+=v0.x; a0.y+=v0.y;  a1.x+=v1.x; a1.y+=v1.y;
    a2.x+=v2.x; a2.y+=v2.y;  a3.x+=v3.x; a3.y+=v3.y;
    a0.x+=v4.x; a0.y+=v4.y;  a1.x+=v5.x; a1.y+=v5.y;
    a2.x+=v6.x; a2.y+=v6.y;  a3.x+=v7.x; a3.y+=v7.y;
  }
  for (; e + 2 <= e1; e += 2){
    int c0=col[e], c1=col[e+1];
    float2 v0=tsp[(size_t)c0*128], v1=tsp[(size_t)c1*128];
    a0.x+=v0.x; a0.y+=v0.y;  a1.x+=v1.x; a1.y+=v1.y;
  }
  if (e < e1){
    float2 v = tsp[(size_t)col[e]*128];
    a0.x+=v.x; a0.y+=v.y;
  }

  a0.x += a1.x + a2.x + a3.x;
  a0.y += a1.y + a2.y + a3.y;
  ((float2*)acc)[(size_t)w*128 + half*64 + lane] = a0;
}

// ---------------- final: out[v] = relu(dinv*acc + b) . Wc + bc ----------------
__global__ __launch_bounds__(256) void k_out(
  const float* __restrict__ acc, const float* __restrict__ bias,
  const float* __restrict__ Wc, const float* __restrict__ bc,
  const float* __restrict__ dinv, float* __restrict__ out, int n)
{
  int w = (int)((blockIdx.x*256 + threadIdx.x) >> 6);
  int lane = threadIdx.x & 63;
  if (w >= n) return;
  float dv = dinv[w];
  float4 a  = ((const float4*)acc)[(size_t)w*64 + lane];
  float4 bb = ((const float4*)bias)[lane];
  float4 wc = ((const float4*)Wc)[lane];
  float s = fmaxf(fmaf(dv, a.x, bb.x), 0.f)*wc.x
          + fmaxf(fmaf(dv, a.y, bb.y), 0.f)*wc.y
          + fmaxf(fmaf(dv, a.z, bb.z), 0.f)*wc.z
          + fmaxf(fmaf(dv, a.w, bb.w), 0.f)*wc.w;
  #pragma unroll
  for (int off = 32; off; off >>= 1) s += __shfl_down(s, off, 64);
  if (lane == 0) out[w] = s + bc[0];
}

// ---------------- launch ----------------
extern "C" void kernel_launch(void* const* d_in, const int* in_sizes, int n_in,
                              void* d_out, int out_size, void* d_ws, size_t ws_size,
                              hipStream_t stream)
{
  const float* x  = (const float*)d_in[0];
  const int*   ei = (const int*)d_in[1];
  const float* W1 = (const float*)d_in[2];
  const float* b1 = (const float*)d_in[3];
  const float* Wm = (const float*)d_in[4];
  const float* bm = (const float*)d_in[5];
  const float* Wc = (const float*)d_in[6];
  const float* bc = (const float*)d_in[7];
  float* out = (float*)d_out;
  const int N = in_sizes[0];
  const ll  E = in_sizes[1] / 2;

  char* ws = (char*)d_ws;
  size_t off = 0;
  auto carve = [&](size_t bytes)->char*{
    char* p = ws + off; off += (bytes + 255) & ~(size_t)255; return p;
  };
  int*   cnt     = (int*)  carve((size_t)N*4);
  int*   row_ptr = (int*)  carve((size_t)(N+1)*4);
  int*   fill    = (int*)  carve((size_t)N*4);
  float* dinv    = (float*)carve((size_t)N*4);
  float* xd      = (float*)carve((size_t)N*4);
  float* g       = (float*)carve((size_t)N*4);
  int*   flag    = (int*)  carve(256);
  short* Bt      = (short*)carve((size_t)2*8192*8*2);   // 256 KB
  int*   col     = (int*)  carve((size_t)E*4);
  float* ts      = (float*)carve((size_t)N*HID*4);
  float* acc     = (float*)carve((size_t)N*HID*4);
  if (off > ws_size){
    k_diag<<<(out_size+255)/256, 256, 0, stream>>>(out, out_size, (float)(ws_size >> 20));
    return;
  }

  hipMemsetAsync(cnt, 0, (size_t)N*4, stream);
  k_detect<<<1, 256, 0, stream>>>(ei, flag);
  int eblocks = (int)((E + 255) / 256);
  k_count<<<eblocks, 256, 0, stream>>>(ei, E, flag, cnt);
  k_scan1024<<<1, 1024, 0, stream>>>(cnt, row_ptr, N);
  k_dinv<<<(N+255)/256, 256, 0, stream>>>(cnt, x, dinv, xd, N);
  hipMemcpyAsync(fill, row_ptr, (size_t)N*4, hipMemcpyDeviceToDevice, stream);
  k_place<<<eblocks, 256, 0, stream>>>(ei, E, flag, fill, col);
  k_splitW<<<32, 256, 0, stream>>>(Wm, Bt);
  k_layer1<<<(N+255)/256, 256, 0, stream>>>(xd, row_ptr, col, g, N);

  int gblocks = (N + 63) / 64;
  int sblocks = (N + 3) / 4;
  k_gemm_mfma<0><<<gblocks, 256, 0, stream>>>(g, Bt, b1, W1, dinv, ts, N);
  k_scatter_h<<<sblocks, 256, 0, stream>>>(ts, row_ptr, col, acc, N, 0);
  k_scatter_h<<<sblocks, 256, 0, stream>>>(ts, row_ptr, col, acc, N, 1);
  for (int l = 0; l < 8; ++l){
    k_gemm_mfma<1><<<gblocks, 256, 0, stream>>>(acc, Bt, bm, nullptr, dinv, ts, N);
    k_scatter_h<<<sblocks, 256, 0, stream>>>(ts, row_ptr, col, acc, N, 0);
    k_scatter_h<<<sblocks, 256, 0, stream>>>(ts, row_ptr, col, acc, N, 1);
  }
  k_out<<<sblocks, 256, 0, stream>>>(acc, bm, Wc, bc, dinv, out, N);
}

// Round 5
// 1024.538 us; speedup vs baseline: 1.5664x; 1.5150x over previous
//
#include <hip/hip_runtime.h>

typedef long long ll;
typedef __attribute__((ext_vector_type(8))) short short8;
typedef __attribute__((ext_vector_type(4))) float f32x4;
constexpr int HID = 256;
constexpr int LDSS = 264;   // LDS row stride in shorts: 528B, 16B-aligned, breaks pow2 banks

__device__ inline ushort f2bf(float f){
  uint u = __float_as_uint(f);
  u += 0x7FFFu + ((u >> 16) & 1u);
  return (ushort)(u >> 16);
}

// ---------------- diagnostics ----------------
__global__ void k_diag(float* out, int n, float val){
  int i = blockIdx.x*256 + threadIdx.x;
  if (i < n) out[i] = val;
}

// flag=1 if edge_index is int64 (all high words of first 2048 entries zero)
__global__ void k_detect(const int* ei, int* flag){
  __shared__ int bad;
  if (threadIdx.x == 0) bad = 0;
  __syncthreads();
  for (int i = threadIdx.x; i < 2048; i += 256)
    if (ei[2*i+1] != 0) bad = 1;
  __syncthreads();
  if (threadIdx.x == 0) *flag = bad ? 0 : 1;
}

// ---------------- graph preprocessing ----------------
__global__ void k_count(const int* ei, ll E, const int* flag, int* cnt){
  ll i = (ll)blockIdx.x*256 + threadIdx.x;
  if (i >= E) return;
  int f = *flag;
  int d = f ? (int)((const ll*)ei)[E + i] : ei[E + i];
  atomicAdd(&cnt[d], 1);
}

// ---- multi-block scan: a) per-block sums, b) scan partials, c) per-block exclusive scan ----
__global__ void k_scan_a(const int* __restrict__ cnt, int* __restrict__ bsum, int n){
  __shared__ int s[256];
  int t = threadIdx.x, i = blockIdx.x*256 + t;
  s[t] = (i < n) ? cnt[i] : 0;
  __syncthreads();
  for (int off = 128; off; off >>= 1){
    if (t < off) s[t] += s[t + off];
    __syncthreads();
  }
  if (t == 0) bsum[blockIdx.x] = s[0];
}

__global__ void k_scan_b(const int* __restrict__ bsum, int* __restrict__ boff,
                         int nb, int* __restrict__ row_ptr, int n){
  __shared__ int s[256];
  int t = threadIdx.x;
  int v = (t < nb) ? bsum[t] : 0;
  s[t] = v; __syncthreads();
  for (int off = 1; off < 256; off <<= 1){
    int add = (t >= off) ? s[t - off] : 0;
    __syncthreads();
    s[t] += add;
    __syncthreads();
  }
  if (t < nb) boff[t] = s[t] - v;       // exclusive
  if (t == nb - 1) row_ptr[n] = s[t];   // total
}

__global__ void k_scan_c(const int* __restrict__ cnt, const int* __restrict__ boff,
                         int* __restrict__ row_ptr, int n){
  __shared__ int s[256];
  int t = threadIdx.x, i = blockIdx.x*256 + t;
  int v = (i < n) ? cnt[i] : 0;
  s[t] = v; __syncthreads();
  for (int off = 1; off < 256; off <<= 1){
    int add = (t >= off) ? s[t - off] : 0;
    __syncthreads();
    s[t] += add;
    __syncthreads();
  }
  if (i < n) row_ptr[i] = boff[blockIdx.x] + s[t] - v;
}

__global__ void k_dinv(const int* cnt, const float* x, float* dinv, float* xd, int n){
  int i = blockIdx.x*256 + threadIdx.x;
  if (i >= n) return;
  float dv = 1.0f / sqrtf((float)(cnt[i] + 1));
  dinv[i] = dv;
  xd[i] = x[i] * dv;
}

__global__ void k_place(const int* ei, ll E, const int* flag, int* fill, int* col){
  ll i = (ll)blockIdx.x*256 + threadIdx.x;
  if (i >= E) return;
  int f = *flag;
  int s, d;
  if (f){ const ll* e64 = (const ll*)ei; s = (int)e64[i]; d = (int)e64[E + i]; }
  else  { s = ei[i]; d = ei[E + i]; }
  int p = atomicAdd(&fill[d], 1);
  col[p] = s;
}

// layer 1 is rank-1: g[d] = xd[d] + sum_{s->d} xd[s]  (fp32 gather — tiny)
__global__ void k_layer1(const float* __restrict__ xd, const int* __restrict__ row_ptr,
                         const int* __restrict__ col, float* __restrict__ g, int n){
  int i = blockIdx.x*256 + threadIdx.x;
  if (i >= n) return;
  float s = xd[i];
  int e0 = row_ptr[i], e1 = row_ptr[i+1];
  for (int e = e0; e < e1; ++e) s += xd[col[e]];
  g[i] = s;
}

// ---------------- W split: fp32 -> (hi,lo) bf16, MFMA-fragment-major ----------------
__global__ void k_splitW(const float* __restrict__ W, short* __restrict__ Bt){
  int idx = blockIdx.x*256 + threadIdx.x;
  if (idx >= 16*8*64) return;
  int nb = idx >> 9, kc = (idx >> 6) & 7, l = idx & 63;
  short8 hi, lo;
  #pragma unroll
  for (int j = 0; j < 8; ++j){
    int k = kc*32 + ((l >> 4) * 8) + j;
    int c = nb*16 + (l & 15);
    float wv = W[k*HID + c];
    ushort h = f2bf(wv);
    float hf = __uint_as_float((uint)h << 16);
    hi[j] = (short)h;
    lo[j] = (short)f2bf(wv - hf);
  }
  ((short8*)Bt)[idx] = hi;
  ((short8*)Bt)[8192 + idx] = lo;
}

// ---------------- MFMA GEMM: ts_bf = bf16( relu-transform(Ain) @ W * dinv_row ) ----------------
template<int MODE>
__global__ __launch_bounds__(256, 2) void k_gemm_mfma(
  const float* __restrict__ Ain, const short* __restrict__ Bt,
  const float* __restrict__ bias, const float* __restrict__ W1,
  const float* __restrict__ dinv, ushort* __restrict__ ts_bf, int n)
{
  __shared__ short Ah[64*LDSS];
  __shared__ short Al[64*LDSS];
  int t = threadIdx.x;
  int r0 = blockIdx.x * 64;

  #pragma unroll
  for (int i = 0; i < 8; ++i){
    int id  = i*256 + t;
    int row = id >> 5;
    int c16 = id & 31;
    int v   = r0 + row;
    short8 hi8 = {0,0,0,0,0,0,0,0}, lo8 = {0,0,0,0,0,0,0,0};
    if (v < n){
      float dv = dinv[v];
      float vals[8];
      if (MODE == 0){
        float gv = dv * Ain[v];
        const float4* wp = (const float4*)(W1 + c16*8);
        const float4* bp = (const float4*)(bias + c16*8);
        float4 w0 = wp[0], w1 = wp[1], b0 = bp[0], b1 = bp[1];
        vals[0]=fmaf(gv,w0.x,b0.x); vals[1]=fmaf(gv,w0.y,b0.y);
        vals[2]=fmaf(gv,w0.z,b0.z); vals[3]=fmaf(gv,w0.w,b0.w);
        vals[4]=fmaf(gv,w1.x,b1.x); vals[5]=fmaf(gv,w1.y,b1.y);
        vals[6]=fmaf(gv,w1.z,b1.z); vals[7]=fmaf(gv,w1.w,b1.w);
      } else {
        const float4* ap = (const float4*)(Ain + (size_t)v*HID + c16*8);
        const float4* bp = (const float4*)(bias + c16*8);
        float4 a0 = ap[0], a1 = ap[1], b0 = bp[0], b1 = bp[1];
        vals[0]=fmaf(dv,a0.x,b0.x); vals[1]=fmaf(dv,a0.y,b0.y);
        vals[2]=fmaf(dv,a0.z,b0.z); vals[3]=fmaf(dv,a0.w,b0.w);
        vals[4]=fmaf(dv,a1.x,b1.x); vals[5]=fmaf(dv,a1.y,b1.y);
        vals[6]=fmaf(dv,a1.z,b1.z); vals[7]=fmaf(dv,a1.w,b1.w);
      }
      #pragma unroll
      for (int j = 0; j < 8; ++j){
        float a = fmaxf(vals[j], 0.f);
        ushort h = f2bf(a);
        float hf = __uint_as_float((uint)h << 16);
        hi8[j] = (short)h;
        lo8[j] = (short)f2bf(a - hf);
      }
    }
    int off = row*LDSS + c16*8;
    *(short8*)&Ah[off] = hi8;
    *(short8*)&Al[off] = lo8;
  }
  __syncthreads();

  int l = t & 63, w = t >> 6;
  const short8* Btv = (const short8*)Bt;
  f32x4 acc[4][4];
  #pragma unroll
  for (int m = 0; m < 4; ++m)
    #pragma unroll
    for (int nf = 0; nf < 4; ++nf)
      acc[m][nf] = (f32x4){0.f,0.f,0.f,0.f};

  for (int kc = 0; kc < 8; ++kc){
    short8 ah[4], al[4];
    #pragma unroll
    for (int m = 0; m < 4; ++m){
      int row = m*16 + (l & 15);
      int off = row*LDSS + (kc*4 + (l >> 4))*8;
      ah[m] = *(const short8*)&Ah[off];
      al[m] = *(const short8*)&Al[off];
    }
    #pragma unroll
    for (int nf = 0; nf < 4; ++nf){
      int nb = w*4 + nf;
      short8 bh = Btv[(size_t)(nb*8 + kc)*64 + l];
      short8 bl = Btv[(size_t)8192 + (nb*8 + kc)*64 + l];
      #pragma unroll
      for (int m = 0; m < 4; ++m){
        acc[m][nf] = __builtin_amdgcn_mfma_f32_16x16x32_bf16(ah[m], bh, acc[m][nf], 0,0,0);
        acc[m][nf] = __builtin_amdgcn_mfma_f32_16x16x32_bf16(al[m], bh, acc[m][nf], 0,0,0);
        acc[m][nf] = __builtin_amdgcn_mfma_f32_16x16x32_bf16(ah[m], bl, acc[m][nf], 0,0,0);
      }
    }
  }

  #pragma unroll
  for (int m = 0; m < 4; ++m){
    int rowb = r0 + m*16 + ((l >> 4)*4);
    #pragma unroll
    for (int r = 0; r < 4; ++r){
      int v = rowb + r;
      if (v < n){
        float dv = dinv[v];
        #pragma unroll
        for (int nf = 0; nf < 4; ++nf){
          int colb = w*64 + nf*16 + (l & 15);
          ts_bf[(size_t)v*HID + colb] = f2bf(dv * acc[m][nf][r]);
        }
      }
    }
  }
}

// ---------------- propagate: acc[d] = ts[d] + sum ts[col[e]], ts in bf16 ----------------
// 8B/lane (4 bf16 features), fp32 accumulate. Fabric-BW-bound: bytes halved vs fp32.
__device__ inline void bfacc(uint2 u, float4& a){
  a.x += __uint_as_float(u.x << 16);
  a.y += __uint_as_float(u.x & 0xFFFF0000u);
  a.z += __uint_as_float(u.y << 16);
  a.w += __uint_as_float(u.y & 0xFFFF0000u);
}

__global__ __launch_bounds__(256, 4) void k_scatter_bf(
  const ushort* __restrict__ ts_bf, const int* __restrict__ row_ptr,
  const int* __restrict__ col, float* __restrict__ acc, int n)
{
  int w = (int)((blockIdx.x*256 + threadIdx.x) >> 6);
  int lane = threadIdx.x & 63;
  if (w >= n) return;
  const uint2* tsp = ((const uint2*)ts_bf) + lane;   // row c at + c*64
  int e0 = row_ptr[w], e1 = row_ptr[w+1];

  float4 a0 = make_float4(0.f,0.f,0.f,0.f);
  float4 a1 = make_float4(0.f,0.f,0.f,0.f);
  float4 a2 = make_float4(0.f,0.f,0.f,0.f);
  float4 a3 = make_float4(0.f,0.f,0.f,0.f);
  bfacc(tsp[(size_t)w*64], a0);                      // self-loop term

  int e = e0;
  for (; e + 4 <= e1; e += 4){
    int c0 = col[e+0], c1 = col[e+1], c2 = col[e+2], c3 = col[e+3];
    uint2 v0 = tsp[(size_t)c0*64];
    uint2 v1 = tsp[(size_t)c1*64];
    uint2 v2 = tsp[(size_t)c2*64];
    uint2 v3 = tsp[(size_t)c3*64];
    bfacc(v0, a0); bfacc(v1, a1); bfacc(v2, a2); bfacc(v3, a3);
  }
  for (; e < e1; ++e){
    uint2 v = tsp[(size_t)col[e]*64];
    bfacc(v, a0);
  }

  a0.x += a1.x + a2.x + a3.x;
  a0.y += a1.y + a2.y + a3.y;
  a0.z += a1.z + a2.z + a3.z;
  a0.w += a1.w + a2.w + a3.w;
  ((float4*)acc)[(size_t)w*64 + lane] = a0;
}

// ---------------- final: out[v] = relu(dinv*acc + b) . Wc + bc ----------------
__global__ __launch_bounds__(256) void k_out(
  const float* __restrict__ acc, const float* __restrict__ bias,
  const float* __restrict__ Wc, const float* __restrict__ bc,
  const float* __restrict__ dinv, float* __restrict__ out, int n)
{
  int w = (int)((blockIdx.x*256 + threadIdx.x) >> 6);
  int lane = threadIdx.x & 63;
  if (w >= n) return;
  float dv = dinv[w];
  float4 a  = ((const float4*)acc)[(size_t)w*64 + lane];
  float4 bb = ((const float4*)bias)[lane];
  float4 wc = ((const float4*)Wc)[lane];
  float s = fmaxf(fmaf(dv, a.x, bb.x), 0.f)*wc.x
          + fmaxf(fmaf(dv, a.y, bb.y), 0.f)*wc.y
          + fmaxf(fmaf(dv, a.z, bb.z), 0.f)*wc.z
          + fmaxf(fmaf(dv, a.w, bb.w), 0.f)*wc.w;
  #pragma unroll
  for (int off = 32; off; off >>= 1) s += __shfl_down(s, off, 64);
  if (lane == 0) out[w] = s + bc[0];
}

// ---------------- launch ----------------
extern "C" void kernel_launch(void* const* d_in, const int* in_sizes, int n_in,
                              void* d_out, int out_size, void* d_ws, size_t ws_size,
                              hipStream_t stream)
{
  const float* x  = (const float*)d_in[0];
  const int*   ei = (const int*)d_in[1];
  const float* W1 = (const float*)d_in[2];
  const float* b1 = (const float*)d_in[3];
  const float* Wm = (const float*)d_in[4];
  const float* bm = (const float*)d_in[5];
  const float* Wc = (const float*)d_in[6];
  const float* bc = (const float*)d_in[7];
  float* out = (float*)d_out;
  const int N = in_sizes[0];
  const ll  E = in_sizes[1] / 2;

  char* ws = (char*)d_ws;
  size_t off = 0;
  auto carve = [&](size_t bytes)->char*{
    char* p = ws + off; off += (bytes + 255) & ~(size_t)255; return p;
  };
  int*   cnt     = (int*)  carve((size_t)N*4);
  int*   row_ptr = (int*)  carve((size_t)(N+1)*4);
  int*   fill    = (int*)  carve((size_t)N*4);
  float* dinv    = (float*)carve((size_t)N*4);
  float* xd      = (float*)carve((size_t)N*4);
  float* g       = (float*)carve((size_t)N*4);
  int*   flag    = (int*)  carve(256);
  int*   bsum    = (int*)  carve(1024);
  int*   boff    = (int*)  carve(1024);
  short* Bt      = (short*)carve((size_t)2*8192*8*2);   // 256 KB
  int*   col     = (int*)  carve((size_t)E*4);
  ushort* ts_bf  = (ushort*)carve((size_t)N*HID*2);     // 25.6 MB
  float* acc     = (float*)carve((size_t)N*HID*4);      // 51.2 MB
  if (off > ws_size){
    k_diag<<<(out_size+255)/256, 256, 0, stream>>>(out, out_size, (float)(ws_size >> 20));
    return;
  }

  hipMemsetAsync(cnt, 0, (size_t)N*4, stream);
  k_detect<<<1, 256, 0, stream>>>(ei, flag);
  int eblocks = (int)((E + 255) / 256);
  k_count<<<eblocks, 256, 0, stream>>>(ei, E, flag, cnt);
  int nb = (N + 255) / 256;
  k_scan_a<<<nb, 256, 0, stream>>>(cnt, bsum, N);
  k_scan_b<<<1, 256, 0, stream>>>(bsum, boff, nb, row_ptr, N);
  k_scan_c<<<nb, 256, 0, stream>>>(cnt, boff, row_ptr, N);
  k_dinv<<<(N+255)/256, 256, 0, stream>>>(cnt, x, dinv, xd, N);
  hipMemcpyAsync(fill, row_ptr, (size_t)N*4, hipMemcpyDeviceToDevice, stream);
  k_place<<<eblocks, 256, 0, stream>>>(ei, E, flag, fill, col);
  k_splitW<<<32, 256, 0, stream>>>(Wm, Bt);
  k_layer1<<<(N+255)/256, 256, 0, stream>>>(xd, row_ptr, col, g, N);

  int gblocks = (N + 63) / 64;
  int sblocks = (N + 3) / 4;
  k_gemm_mfma<0><<<gblocks, 256, 0, stream>>>(g, Bt, b1, W1, dinv, ts_bf, N);
  k_scatter_bf<<<sblocks, 256, 0, stream>>>(ts_bf, row_ptr, col, acc, N);
  for (int l = 0; l < 8; ++l){
    k_gemm_mfma<1><<<gblocks, 256, 0, stream>>>(acc, Bt, bm, nullptr, dinv, ts_bf, N);
    k_scatter_bf<<<sblocks, 256, 0, stream>>>(ts_bf, row_ptr, col, acc, N);
  }
  k_out<<<sblocks, 256, 0, stream>>>(acc, bm, Wc, bc, dinv, out, N);
}

// Round 6
// 868.051 us; speedup vs baseline: 1.8488x; 1.1803x over previous
//
#include <hip/hip_runtime.h>

typedef long long ll;
typedef __attribute__((ext_vector_type(8))) short short8;
typedef __attribute__((ext_vector_type(4))) float f32x4;
constexpr int HID = 256;
constexpr int LDSS = 264;   // LDS row stride in shorts: 528B, 16B-aligned, ~2-way banks (free)

__device__ inline ushort f2bf(float f){
  uint u = __float_as_uint(f);
  u += 0x7FFFu + ((u >> 16) & 1u);
  return (ushort)(u >> 16);
}

// ---------------- diagnostics ----------------
__global__ void k_diag(float* out, int n, float val){
  int i = blockIdx.x*256 + threadIdx.x;
  if (i < n) out[i] = val;
}

// flag=1 if edge_index is int64 (all high words of first 2048 entries zero)
__global__ void k_detect(const int* ei, int* flag){
  __shared__ int bad;
  if (threadIdx.x == 0) bad = 0;
  __syncthreads();
  for (int i = threadIdx.x; i < 2048; i += 256)
    if (ei[2*i+1] != 0) bad = 1;
  __syncthreads();
  if (threadIdx.x == 0) *flag = bad ? 0 : 1;
}

// ---------------- graph preprocessing ----------------
__global__ void k_count(const int* ei, ll E, const int* flag, int* cnt){
  ll i = (ll)blockIdx.x*256 + threadIdx.x;
  if (i >= E) return;
  int f = *flag;
  int d = f ? (int)((const ll*)ei)[E + i] : ei[E + i];
  atomicAdd(&cnt[d], 1);
}

// ---- multi-block scan ----
__global__ void k_scan_a(const int* __restrict__ cnt, int* __restrict__ bsum, int n){
  __shared__ int s[256];
  int t = threadIdx.x, i = blockIdx.x*256 + t;
  s[t] = (i < n) ? cnt[i] : 0;
  __syncthreads();
  for (int off = 128; off; off >>= 1){
    if (t < off) s[t] += s[t + off];
    __syncthreads();
  }
  if (t == 0) bsum[blockIdx.x] = s[0];
}

__global__ void k_scan_b(const int* __restrict__ bsum, int* __restrict__ boff,
                         int nb, int* __restrict__ row_ptr, int n){
  __shared__ int s[256];
  int t = threadIdx.x;
  int v = (t < nb) ? bsum[t] : 0;
  s[t] = v; __syncthreads();
  for (int off = 1; off < 256; off <<= 1){
    int add = (t >= off) ? s[t - off] : 0;
    __syncthreads();
    s[t] += add;
    __syncthreads();
  }
  if (t < nb) boff[t] = s[t] - v;
  if (t == nb - 1) row_ptr[n] = s[t];
}

__global__ void k_scan_c(const int* __restrict__ cnt, const int* __restrict__ boff,
                         int* __restrict__ row_ptr, int n){
  __shared__ int s[256];
  int t = threadIdx.x, i = blockIdx.x*256 + t;
  int v = (i < n) ? cnt[i] : 0;
  s[t] = v; __syncthreads();
  for (int off = 1; off < 256; off <<= 1){
    int add = (t >= off) ? s[t - off] : 0;
    __syncthreads();
    s[t] += add;
    __syncthreads();
  }
  if (i < n) row_ptr[i] = boff[blockIdx.x] + s[t] - v;
}

__global__ void k_dinv(const int* cnt, const float* x, float* dinv, float* xd, int n){
  int i = blockIdx.x*256 + threadIdx.x;
  if (i >= n) return;
  float dv = 1.0f / sqrtf((float)(cnt[i] + 1));
  dinv[i] = dv;
  xd[i] = x[i] * dv;
}

__global__ void k_place(const int* ei, ll E, const int* flag, int* fill, int* col){
  ll i = (ll)blockIdx.x*256 + threadIdx.x;
  if (i >= E) return;
  int f = *flag;
  int s, d;
  if (f){ const ll* e64 = (const ll*)ei; s = (int)e64[i]; d = (int)e64[E + i]; }
  else  { s = ei[i]; d = ei[E + i]; }
  int p = atomicAdd(&fill[d], 1);
  col[p] = s;
}

// layer 1 is rank-1: g[d] = xd[d] + sum_{s->d} xd[s]
__global__ void k_layer1(const float* __restrict__ xd, const int* __restrict__ row_ptr,
                         const int* __restrict__ col, float* __restrict__ g, int n){
  int i = blockIdx.x*256 + threadIdx.x;
  if (i >= n) return;
  float s = xd[i];
  int e0 = row_ptr[i], e1 = row_ptr[i+1];
  for (int e = e0; e < e1; ++e) s += xd[col[e]];
  g[i] = s;
}

// ---------------- W split: fp32 -> (hi,lo) bf16, MFMA-fragment-major ----------------
__global__ void k_splitW(const float* __restrict__ W, short* __restrict__ Bt){
  int idx = blockIdx.x*256 + threadIdx.x;
  if (idx >= 16*8*64) return;
  int nb = idx >> 9, kc = (idx >> 6) & 7, l = idx & 63;
  short8 hi, lo;
  #pragma unroll
  for (int j = 0; j < 8; ++j){
    int k = kc*32 + ((l >> 4) * 8) + j;
    int c = nb*16 + (l & 15);
    float wv = W[k*HID + c];
    ushort h = f2bf(wv);
    float hf = __uint_as_float((uint)h << 16);
    hi[j] = (short)h;
    lo[j] = (short)f2bf(wv - hf);
  }
  ((short8*)Bt)[idx] = hi;
  ((short8*)Bt)[8192 + idx] = lo;
}

// ---------------- MFMA GEMM: ts_bf = bf16( (A @ W) * dinv_row ) ----------------
// MODE 0: A[v][k] = bf16(relu(dinv[v]*g[v]*W1[k] + b1[k]))   (computed inline from scalar g)
// MODE 1: A = Abf (bf16, transform already applied by scatter epilogue) — pure copy staging
// W = Bh + Bl exact (hi/lo bf16 split): C = Ah*Bh + Ah*Bl, fp32 accumulate.
template<int MODE>
__global__ __launch_bounds__(256, 4) void k_gemm_mfma(
  const void* __restrict__ Ain, const short* __restrict__ Bt,
  const float* __restrict__ bias, const float* __restrict__ W1,
  const float* __restrict__ dinv, ushort* __restrict__ ts_bf, int n)
{
  __shared__ short Ah[64*LDSS];   // 33.8 KB
  int t = threadIdx.x;
  int r0 = blockIdx.x * 64;

  // ---- stage A tile: 64 rows x 256 bf16 ----
  #pragma unroll
  for (int i = 0; i < 8; ++i){
    int id  = i*256 + t;           // 16B-chunk id, 0..2047
    int row = id >> 5;             // 0..63
    int c16 = id & 31;             // 16B chunk within row (8 features)
    int v   = r0 + row;
    short8 hi8 = {0,0,0,0,0,0,0,0};
    if (v < n){
      if (MODE == 0){
        float gv = dinv[v] * ((const float*)Ain)[v];
        const float4* wp = (const float4*)(W1 + c16*8);
        const float4* bp = (const float4*)(bias + c16*8);
        float4 w0 = wp[0], w1 = wp[1], b0 = bp[0], b1 = bp[1];
        hi8[0] = (short)f2bf(fmaxf(fmaf(gv,w0.x,b0.x), 0.f));
        hi8[1] = (short)f2bf(fmaxf(fmaf(gv,w0.y,b0.y), 0.f));
        hi8[2] = (short)f2bf(fmaxf(fmaf(gv,w0.z,b0.z), 0.f));
        hi8[3] = (short)f2bf(fmaxf(fmaf(gv,w0.w,b0.w), 0.f));
        hi8[4] = (short)f2bf(fmaxf(fmaf(gv,w1.x,b1.x), 0.f));
        hi8[5] = (short)f2bf(fmaxf(fmaf(gv,w1.y,b1.y), 0.f));
        hi8[6] = (short)f2bf(fmaxf(fmaf(gv,w1.z,b1.z), 0.f));
        hi8[7] = (short)f2bf(fmaxf(fmaf(gv,w1.w,b1.w), 0.f));
      } else {
        hi8 = ((const short8*)Ain)[(size_t)v*32 + c16];
      }
    }
    *(short8*)&Ah[row*LDSS + c16*8] = hi8;
  }
  __syncthreads();

  // ---- MFMA: wave w covers cols [w*64, w*64+64) ----
  int l = t & 63, w = t >> 6;
  const short8* Btv = (const short8*)Bt;
  f32x4 acc[4][4];
  #pragma unroll
  for (int m = 0; m < 4; ++m)
    #pragma unroll
    for (int nf = 0; nf < 4; ++nf)
      acc[m][nf] = (f32x4){0.f,0.f,0.f,0.f};

  for (int kc = 0; kc < 8; ++kc){
    short8 ah[4];
    #pragma unroll
    for (int m = 0; m < 4; ++m){
      int row = m*16 + (l & 15);
      ah[m] = *(const short8*)&Ah[row*LDSS + (kc*4 + (l >> 4))*8];
    }
    #pragma unroll
    for (int nf = 0; nf < 4; ++nf){
      int nb = w*4 + nf;
      short8 bh = Btv[(size_t)(nb*8 + kc)*64 + l];
      short8 bl = Btv[(size_t)8192 + (nb*8 + kc)*64 + l];
      #pragma unroll
      for (int m = 0; m < 4; ++m){
        acc[m][nf] = __builtin_amdgcn_mfma_f32_16x16x32_bf16(ah[m], bh, acc[m][nf], 0,0,0);
        acc[m][nf] = __builtin_amdgcn_mfma_f32_16x16x32_bf16(ah[m], bl, acc[m][nf], 0,0,0);
      }
    }
  }

  // ---- store ts_bf, pre-scaled by dinv[src] ----
  #pragma unroll
  for (int m = 0; m < 4; ++m){
    int rowb = r0 + m*16 + ((l >> 4)*4);
    #pragma unroll
    for (int r = 0; r < 4; ++r){
      int v = rowb + r;
      if (v < n){
        float dv = dinv[v];
        #pragma unroll
        for (int nf = 0; nf < 4; ++nf){
          int colb = w*64 + nf*16 + (l & 15);
          ts_bf[(size_t)v*HID + colb] = f2bf(dv * acc[m][nf][r]);
        }
      }
    }
  }
}

// ---------------- propagate + fused transform ----------------
// sum = ts[d] + sum_{e} ts[col[e]]  (fp32 accum over bf16 rows)
// Abf[d] = bf16( relu(dinv[d]*sum + b) )   — the next layer's A, ready for GEMM
__device__ inline void bfacc(uint2 u, float4& a){
  a.x += __uint_as_float(u.x << 16);
  a.y += __uint_as_float(u.x & 0xFFFF0000u);
  a.z += __uint_as_float(u.y << 16);
  a.w += __uint_as_float(u.y & 0xFFFF0000u);
}

__global__ __launch_bounds__(256, 4) void k_scatter_bf(
  const ushort* __restrict__ ts_bf, const int* __restrict__ row_ptr,
  const int* __restrict__ col, const float* __restrict__ bias,
  const float* __restrict__ dinv, ushort* __restrict__ Abf, int n)
{
  int w = (int)((blockIdx.x*256 + threadIdx.x) >> 6);
  int lane = threadIdx.x & 63;
  if (w >= n) return;
  const uint2* tsp = ((const uint2*)ts_bf) + lane;   // row c at + c*64
  int e0 = row_ptr[w], e1 = row_ptr[w+1];

  float4 a0 = make_float4(0.f,0.f,0.f,0.f);
  float4 a1 = make_float4(0.f,0.f,0.f,0.f);
  float4 a2 = make_float4(0.f,0.f,0.f,0.f);
  float4 a3 = make_float4(0.f,0.f,0.f,0.f);
  bfacc(tsp[(size_t)w*64], a0);                      // self-loop term

  int e = e0;
  for (; e + 4 <= e1; e += 4){
    int c0 = col[e+0], c1 = col[e+1], c2 = col[e+2], c3 = col[e+3];
    uint2 v0 = tsp[(size_t)c0*64];
    uint2 v1 = tsp[(size_t)c1*64];
    uint2 v2 = tsp[(size_t)c2*64];
    uint2 v3 = tsp[(size_t)c3*64];
    bfacc(v0, a0); bfacc(v1, a1); bfacc(v2, a2); bfacc(v3, a3);
  }
  for (; e < e1; ++e){
    uint2 v = tsp[(size_t)col[e]*64];
    bfacc(v, a0);
  }

  a0.x += a1.x + a2.x + a3.x;
  a0.y += a1.y + a2.y + a3.y;
  a0.z += a1.z + a2.z + a3.z;
  a0.w += a1.w + a2.w + a3.w;

  // fused transform: next A = bf16(relu(dinv*sum + b))
  float dv = dinv[w];
  float4 bb = ((const float4*)bias)[lane];
  uint2 o;
  o.x = (uint)f2bf(fmaxf(fmaf(dv, a0.x, bb.x), 0.f))
      | ((uint)f2bf(fmaxf(fmaf(dv, a0.y, bb.y), 0.f)) << 16);
  o.y = (uint)f2bf(fmaxf(fmaf(dv, a0.z, bb.z), 0.f))
      | ((uint)f2bf(fmaxf(fmaf(dv, a0.w, bb.w), 0.f)) << 16);
  ((uint2*)Abf)[(size_t)w*64 + lane] = o;
}

// ---------------- final: out[v] = Abf[v] . Wc + bc  (transform already fused) ----------------
__global__ __launch_bounds__(256) void k_out(
  const ushort* __restrict__ Abf, const float* __restrict__ Wc,
  const float* __restrict__ bc, float* __restrict__ out, int n)
{
  int w = (int)((blockIdx.x*256 + threadIdx.x) >> 6);
  int lane = threadIdx.x & 63;
  if (w >= n) return;
  uint2 u = ((const uint2*)Abf)[(size_t)w*64 + lane];
  float4 wc = ((const float4*)Wc)[lane];
  float s = __uint_as_float(u.x << 16)          * wc.x
          + __uint_as_float(u.x & 0xFFFF0000u)  * wc.y
          + __uint_as_float(u.y << 16)          * wc.z
          + __uint_as_float(u.y & 0xFFFF0000u)  * wc.w;
  #pragma unroll
  for (int off = 32; off; off >>= 1) s += __shfl_down(s, off, 64);
  if (lane == 0) out[w] = s + bc[0];
}

// ---------------- launch ----------------
extern "C" void kernel_launch(void* const* d_in, const int* in_sizes, int n_in,
                              void* d_out, int out_size, void* d_ws, size_t ws_size,
                              hipStream_t stream)
{
  const float* x  = (const float*)d_in[0];
  const int*   ei = (const int*)d_in[1];
  const float* W1 = (const float*)d_in[2];
  const float* b1 = (const float*)d_in[3];
  const float* Wm = (const float*)d_in[4];
  const float* bm = (const float*)d_in[5];
  const float* Wc = (const float*)d_in[6];
  const float* bc = (const float*)d_in[7];
  float* out = (float*)d_out;
  const int N = in_sizes[0];
  const ll  E = in_sizes[1] / 2;

  char* ws = (char*)d_ws;
  size_t off = 0;
  auto carve = [&](size_t bytes)->char*{
    char* p = ws + off; off += (bytes + 255) & ~(size_t)255; return p;
  };
  int*   cnt     = (int*)  carve((size_t)N*4);
  int*   row_ptr = (int*)  carve((size_t)(N+1)*4);
  int*   fill    = (int*)  carve((size_t)N*4);
  float* dinv    = (float*)carve((size_t)N*4);
  float* xd      = (float*)carve((size_t)N*4);
  float* g       = (float*)carve((size_t)N*4);
  int*   flag    = (int*)  carve(256);
  int*   bsum    = (int*)  carve(1024);
  int*   boff    = (int*)  carve(1024);
  short* Bt      = (short*)carve((size_t)2*8192*8*2);   // 256 KB
  int*   col     = (int*)  carve((size_t)E*4);
  ushort* ts_bf  = (ushort*)carve((size_t)N*HID*2);     // 25.6 MB
  ushort* Abf    = (ushort*)carve((size_t)N*HID*2);     // 25.6 MB
  if (off > ws_size){
    k_diag<<<(out_size+255)/256, 256, 0, stream>>>(out, out_size, (float)(ws_size >> 20));
    return;
  }

  hipMemsetAsync(cnt, 0, (size_t)N*4, stream);
  k_detect<<<1, 256, 0, stream>>>(ei, flag);
  int eblocks = (int)((E + 255) / 256);
  k_count<<<eblocks, 256, 0, stream>>>(ei, E, flag, cnt);
  int nb = (N + 255) / 256;
  k_scan_a<<<nb, 256, 0, stream>>>(cnt, bsum, N);
  k_scan_b<<<1, 256, 0, stream>>>(bsum, boff, nb, row_ptr, N);
  k_scan_c<<<nb, 256, 0, stream>>>(cnt, boff, row_ptr, N);
  k_dinv<<<(N+255)/256, 256, 0, stream>>>(cnt, x, dinv, xd, N);
  hipMemcpyAsync(fill, row_ptr, (size_t)N*4, hipMemcpyDeviceToDevice, stream);
  k_place<<<eblocks, 256, 0, stream>>>(ei, E, flag, fill, col);
  k_splitW<<<32, 256, 0, stream>>>(Wm, Bt);
  k_layer1<<<(N+255)/256, 256, 0, stream>>>(xd, row_ptr, col, g, N);

  int gblocks = (N + 63) / 64;
  int sblocks = (N + 3) / 4;
  // conv1+conv2 GEMM (A computed inline from rank-1 g), then propagate+transform
  k_gemm_mfma<0><<<gblocks, 256, 0, stream>>>(g, Bt, b1, W1, dinv, ts_bf, N);
  k_scatter_bf<<<sblocks, 256, 0, stream>>>(ts_bf, row_ptr, col, bm, dinv, Abf, N);
  // conv3..10
  for (int l = 0; l < 8; ++l){
    k_gemm_mfma<1><<<gblocks, 256, 0, stream>>>(Abf, Bt, bm, nullptr, dinv, ts_bf, N);
    k_scatter_bf<<<sblocks, 256, 0, stream>>>(ts_bf, row_ptr, col, bm, dinv, Abf, N);
  }
  k_out<<<sblocks, 256, 0, stream>>>(Abf, Wc, bc, out, N);
}